// Round 5
// baseline (266.417 us; speedup 1.0000x reference)
//
#include <hip/hip_runtime.h>
#include <cstdint>
#include <cstddef>

#define M_TOT 16384   // B*S = 4*4096
#define K_DIM 2048    // H
#define N_HALF 1024   // H/2
#define NT 32         // K tiles of BK=64
#define L2T 0.012976281620653759f  // log2(10000)/1024

typedef short bf16x8 __attribute__((ext_vector_type(8)));
typedef float f32x4 __attribute__((ext_vector_type(4)));
typedef unsigned short u16x4 __attribute__((ext_vector_type(4)));

__device__ __forceinline__ unsigned short f2bf(float f) {
    unsigned int u = __builtin_bit_cast(unsigned int, f);
    u += 0x7fffu + ((u >> 16) & 1u);   // RNE (no NaN inputs)
    return (unsigned short)(u >> 16);
}

// One launch converts both x and W (fp32 -> bf16), grid-stride.
__global__ __launch_bounds__(256) void cvt_f32_bf16_2(const float4* __restrict__ inA,
                                                      u16x4* __restrict__ outA, int n4A,
                                                      const float4* __restrict__ inB,
                                                      u16x4* __restrict__ outB, int n4B) {
    int idx = blockIdx.x * 256 + threadIdx.x;
    int stride = gridDim.x * 256;
    int tot = n4A + n4B;
    for (int i = idx; i < tot; i += stride) {
        const float4 v = (i < n4A) ? inA[i] : inB[i - n4A];
        u16x4 o;
        o.x = f2bf(v.x); o.y = f2bf(v.y); o.z = f2bf(v.z); o.w = f2bf(v.w);
        if (i < n4A) outA[i] = o; else outB[i - n4A] = o;
    }
}

#define GLD16(g, l) __builtin_amdgcn_global_load_lds( \
    (const __attribute__((address_space(1))) void*)(g), \
    (__attribute__((address_space(3))) void*)(l), 16, 0, 0)

#define MFMA16x16(a, b, c) __builtin_amdgcn_mfma_f32_16x16x32_bf16((a), (b), (c), 0, 0, 0)
#define VMCNT6 asm volatile("s_waitcnt vmcnt(6)" ::: "memory")
#define BAR    __builtin_amdgcn_s_barrier()
#define KCLAMP(k) ((k) < NT ? (k) : NT - 1)

// 256x(128low+128high) block tile, BK=64, 512 thr (8 waves: 2M x 4N),
// double-buffered 128 KiB LDS, 4 phases/K-tile, READ-AHEAD pipeline:
// phase p issues ds_reads for phase p+1's MFMA (Gray-coded quadrants
// M0(A0,B0)->M1(A0,B1)->M2(A1,B0)->M3(A1,B1)), so LDS drain hides under
// the current MFMA cluster. Stage stream = read stream with lag 4 phases,
// uniform vmcnt(6) per phase (8 loads outstanding -> retire next read's unit).
// XOR-swizzled LDS rows (swizzle pre-applied on global src; linear LDS dst).
__global__ __launch_bounds__(512, 2)
void gemm_rope(const unsigned short* __restrict__ Xb,
               const unsigned short* __restrict__ Wb,
               const float* __restrict__ bias,
               float* __restrict__ out)
{
    __shared__ __align__(16) unsigned short As[2][256][64];  // 64 KiB
    __shared__ __align__(16) unsigned short Bs[2][256][64];  // 64 KiB

    const int tid  = threadIdx.x;
    const int lane = tid & 63;
    const int wave = tid >> 6;
    const int wr = wave >> 2;   // 0..1  (row half)
    const int wc = wave & 3;    // 0..3  (col quarter)
    const int fr = lane & 15;
    const int hi = lane >> 4;   // 0..3

    // XCD-aware swizzle (grid=512, 512%8==0 -> bijective)
    const int bid = blockIdx.x;
    const int swz = (bid & 7) * 64 + (bid >> 3);
    const int nb = swz & 7;     // 8 col-pair blocks of 128
    const int mb = swz >> 3;    // 64 row blocks of 256
    const int m0 = mb * 256;
    const int c0 = nb * 128;

    // ---- staging address precompute (linear LDS dst, swizzled global src) ----
    const unsigned short* aSrc[2][2];
    const unsigned short* bSrc[2][2];
    int aDst[2][2], bDst[2][2];
    #pragma unroll
    for (int l = 0; l < 2; ++l) {
        const int c = wave * 128 + l * 64 + lane;       // 16B-chunk index, 0..1023
        // A-unit(qi): rows {qi*64+[0,64)} U {128+qi*64+[0,64)}  (qi=0 -> A0 frag rows, qi=1 -> A1)
        const int seg = c >> 9, within = c & 511;
        const int ris = within >> 3, cch = within & 7;
        const int kch = cch ^ (ris & 7);
        #pragma unroll
        for (int qi = 0; qi < 2; ++qi) {
            const int ldsrow = seg * 128 + qi * 64 + ris;
            aDst[qi][l] = ldsrow * 128 + cch * 16;
            const int grow = m0 + seg * 128 + qi * 64 + ris;
            aSrc[qi][l] = Xb + (size_t)grow * K_DIM + kch * 8;
        }
        // B-unit(qj): rows qj*128+[0,128)  (qj=0 -> B0/low cols, qj=1 -> B1/high cols)
        const int rin = c >> 3, cchb = c & 7;
        const int kchb = cchb ^ (rin & 7);
        #pragma unroll
        for (int qj = 0; qj < 2; ++qj) {
            bDst[qj][l] = (qj * 128 + rin) * 128 + cchb * 16;
            const int wrow = qj * N_HALF + c0 + rin;
            bSrc[qj][l] = Wb + (size_t)wrow * K_DIM + kchb * 8;
        }
    }

#define STAGE_A(q, bb, kk) do { \
    GLD16(aSrc[q][0] + (size_t)(kk) * 64, (char*)&As[bb][0][0] + aDst[q][0]); \
    GLD16(aSrc[q][1] + (size_t)(kk) * 64, (char*)&As[bb][0][0] + aDst[q][1]); \
} while (0)
#define STAGE_B(q, bb, kk) do { \
    GLD16(bSrc[q][0] + (size_t)(kk) * 64, (char*)&Bs[bb][0][0] + bDst[q][0]); \
    GLD16(bSrc[q][1] + (size_t)(kk) * 64, (char*)&Bs[bb][0][0] + bDst[q][1]); \
} while (0)

    // frag-read swizzled k byte-offsets within a 128-B LDS row
    const int xorv = (fr & 7) << 4;
    const int koff0 = (hi * 16) ^ xorv;         // k-slice 0 (k=0..31)
    const int koff1 = (64 + hi * 16) ^ xorv;    // k-slice 1 (k=32..63)

#define RD8(base, row, ko) (*(const bf16x8*)((const char*)(base) + (row) * 128 + (ko)))
#define READ_A(dst, base, rb) do { _Pragma("unroll") \
    for (int i = 0; i < 4; ++i) { \
        dst[i][0] = RD8(base, (rb) + i * 16 + fr, koff0); \
        dst[i][1] = RD8(base, (rb) + i * 16 + fr, koff1); } } while (0)
#define READ_B(dst, base, rb) do { _Pragma("unroll") \
    for (int j = 0; j < 2; ++j) { \
        dst[j][0] = RD8(base, (rb) + j * 16 + fr, koff0); \
        dst[j][1] = RD8(base, (rb) + j * 16 + fr, koff1); } } while (0)

    f32x4 acc[8][4];
    #pragma unroll
    for (int i = 0; i < 8; ++i)
        #pragma unroll
        for (int j = 0; j < 4; ++j)
            acc[i][j] = (f32x4){0.f, 0.f, 0.f, 0.f};

    // static-role frag sets: aP=A0, aQ=A1, bX=B0, bY=B1
    bf16x8 aP[4][2], aQ[4][2], bX[2][2], bY[2][2];

#define CLUSTER(r0, aset, bset, j0) do { \
    __builtin_amdgcn_s_setprio(1); \
    _Pragma("unroll") for (int i = 0; i < 4; ++i) \
      _Pragma("unroll") for (int j = 0; j < 2; ++j) { \
        acc[(r0) + i][(j0) + j] = MFMA16x16(aset[i][0], bset[j][0], acc[(r0) + i][(j0) + j]); \
        acc[(r0) + i][(j0) + j] = MFMA16x16(aset[i][1], bset[j][1], acc[(r0) + i][(j0) + j]); } \
    __builtin_amdgcn_s_setprio(0); } while (0)

    // Phases (tile t in arrays[cur]): read-for-next + stage(lag 4) + vmcnt(6) + bar + MFMA.
#define PHASE0(cur, nxt, t) do { \
    READ_B(bY, &Bs[cur][0][0], 128 + wc * 32); \
    STAGE_B(1, nxt, KCLAMP((t) + 1)); \
    VMCNT6; BAR; \
    CLUSTER(0, aP, bX, 0); } while (0)
#define PHASE1(cur, nxt, t) do { \
    READ_A(aQ, &As[cur][0][0], wr * 128 + 64); \
    STAGE_A(1, nxt, KCLAMP((t) + 1)); \
    VMCNT6; BAR; \
    CLUSTER(0, aP, bY, 2); } while (0)
#define PHASE2(cur, nxt, t) do { \
    READ_A(aP, &As[nxt][0][0], wr * 128); \
    STAGE_A(0, cur, KCLAMP((t) + 2)); \
    VMCNT6; BAR; \
    CLUSTER(4, aQ, bX, 0); } while (0)
#define PHASE3(cur, nxt, t) do { \
    READ_B(bX, &Bs[nxt][0][0], wc * 32); \
    STAGE_B(0, cur, KCLAMP((t) + 2)); \
    VMCNT6; BAR; \
    CLUSTER(4, aQ, bY, 2); } while (0)

    // ---- prologue: prime stage stream + pre-read M0(0)'s operands ----
    STAGE_A(0, 0, 0);   // A0(0)
    STAGE_B(0, 0, 0);   // B0(0)
    STAGE_B(1, 0, 0);   // B1(0)   (read at t0-p0)
    STAGE_A(1, 0, 0);   // A1(0)   (in flight)
    STAGE_A(0, 1, 1);   // A0(1)   (in flight)
    STAGE_B(0, 1, 1);   // B0(1)   (in flight)
    VMCNT6;             // retires A0(0),B0(0),B1(0); 6 loads remain in flight
    BAR;
    READ_A(aP, &As[0][0][0], wr * 128);
    READ_B(bX, &Bs[0][0][0], wc * 32);

    for (int ti = 0; ti < NT / 2; ++ti) {
        const int te = 2 * ti, to = te + 1;
        PHASE0(0, 1, te); PHASE1(0, 1, te); PHASE2(0, 1, te); PHASE3(0, 1, te);
        PHASE0(1, 0, to); PHASE1(1, 0, to); PHASE2(1, 0, to); PHASE3(1, 0, to);
    }
    asm volatile("s_waitcnt vmcnt(0)" ::: "memory");  // drain LDS-DMA before epilogue

    // ---- epilogue: bias + RoPE + 2x, fp32 store ----
    // acc[i][cp] (cp=0,1): col ol = c0 + wc*32 + cp*16 + fr; acc[i][cp+2]: col ol+1024.
    // rows: m = m0 + wr*128 + i*16 + hi*4 + r  (block stays within one 4096-seq)
    const float fs0f = (float)((m0 + wr * 128 + hi * 4) & 4095);
    #pragma unroll
    for (int cp = 0; cp < 2; ++cp) {
        const int ol = c0 + wc * 32 + cp * 16 + fr;
        const float invf = exp2f(-L2T * (float)ol);
        const float bl = bias[ol], bh = bias[ol + N_HALF];
        float cs, sn, c1, s1, c13, s13;
        sincosf(fs0f * invf, &sn, &cs);      // base angle
        sincosf(invf, &s1, &c1);             // +1 row step
        sincosf(13.0f * invf, &s13, &c13);   // +13 (frag-boundary) step
        #pragma unroll
        for (int i = 0; i < 8; ++i) {
            #pragma unroll
            for (int r = 0; r < 4; ++r) {
                const int m = m0 + wr * 128 + i * 16 + hi * 4 + r;
                float* orow = out + (size_t)m * K_DIM + ol;
                const float ql = acc[i][cp][r] + bl;
                const float qh = acc[i][cp + 2][r] + bh;
                orow[0]      = 2.0f * (ql * cs - qh * sn);
                orow[N_HALF] = 2.0f * (qh * cs + ql * sn);
                float nc, ns;
                if (r < 3) { nc = cs * c1 - sn * s1;  ns = sn * c1 + cs * s1; }
                else       { nc = cs * c13 - sn * s13; ns = sn * c13 + cs * s13; }
                cs = nc; sn = ns;
            }
        }
    }
}

// Emergency fallback if workspace is too small: slow but correct fp32 path.
__global__ __launch_bounds__(256) void fallback_fused(const float* __restrict__ x,
                                                      const float* __restrict__ W,
                                                      const float* __restrict__ bias,
                                                      float* __restrict__ out)
{
    __shared__ float xs[K_DIM];
    const int m = blockIdx.x;
    const int tid = threadIdx.x;
    for (int k = tid; k < K_DIM; k += 256) xs[k] = x[(size_t)m * K_DIM + k];
    __syncthreads();
    const float fs = (float)(m & 4095);
    for (int ol = tid; ol < N_HALF; ol += 256) {
        const float* wl = W + (size_t)ol * K_DIM;
        const float* wh = W + (size_t)(ol + N_HALF) * K_DIM;
        float al = 0.f, ah = 0.f;
        for (int k = 0; k < K_DIM; ++k) { al += xs[k] * wl[k]; ah += xs[k] * wh[k]; }
        al += bias[ol]; ah += bias[ol + N_HALF];
        float sn, cs;
        sincosf(fs * exp2f(-L2T * (float)ol), &sn, &cs);
        out[(size_t)m * K_DIM + ol]          = 2.0f * (al * cs - ah * sn);
        out[(size_t)m * K_DIM + ol + N_HALF] = 2.0f * (ah * cs + al * sn);
    }
}

extern "C" void kernel_launch(void* const* d_in, const int* in_sizes, int n_in,
                              void* d_out, int out_size, void* d_ws, size_t ws_size,
                              hipStream_t stream)
{
    const float* x = (const float*)d_in[0];
    const float* W = (const float*)d_in[1];
    const float* b = (const float*)d_in[2];
    float* out = (float*)d_out;

    const size_t nx = (size_t)M_TOT * K_DIM;
    const size_t nw = (size_t)K_DIM * K_DIM;
    const size_t need = (nx + nw) * sizeof(unsigned short);
    if (ws_size < need) {
        fallback_fused<<<M_TOT, 256, 0, stream>>>(x, W, b, out);
        return;
    }
    unsigned short* xb = (unsigned short*)d_ws;
    unsigned short* wb = xb + nx;
    cvt_f32_bf16_2<<<2048, 256, 0, stream>>>((const float4*)x, (u16x4*)xb, (int)(nx / 4),
                                             (const float4*)W, (u16x4*)wb, (int)(nw / 4));
    gemm_rope<<<(M_TOT / 256) * (N_HALF / 128), 512, 0, stream>>>(xb, wb, b, out);
}

// Round 6
// 188.806 us; speedup vs baseline: 1.4111x; 1.4111x over previous
//
#include <hip/hip_runtime.h>
#include <cstdint>
#include <cstddef>

#define M_TOT 16384   // B*S = 4*4096
#define K_DIM 2048    // H
#define N_HALF 1024   // H/2
#define NT 32         // K tiles of BK=64
#define L2T 0.012976281620653759f  // log2(10000)/1024

typedef short bf16x8 __attribute__((ext_vector_type(8)));
typedef float f32x4 __attribute__((ext_vector_type(4)));
typedef unsigned short u16x4 __attribute__((ext_vector_type(4)));

__device__ __forceinline__ unsigned short f2bf(float f) {
    unsigned int u = __builtin_bit_cast(unsigned int, f);
    u += 0x7fffu + ((u >> 16) & 1u);   // RNE (no NaN inputs)
    return (unsigned short)(u >> 16);
}

// One launch converts both x and W (fp32 -> bf16), grid-stride.
__global__ __launch_bounds__(256) void cvt_f32_bf16_2(const float4* __restrict__ inA,
                                                      u16x4* __restrict__ outA, int n4A,
                                                      const float4* __restrict__ inB,
                                                      u16x4* __restrict__ outB, int n4B) {
    int idx = blockIdx.x * 256 + threadIdx.x;
    int stride = gridDim.x * 256;
    int tot = n4A + n4B;
    for (int i = idx; i < tot; i += stride) {
        const float4 v = (i < n4A) ? inA[i] : inB[i - n4A];
        u16x4 o;
        o.x = f2bf(v.x); o.y = f2bf(v.y); o.z = f2bf(v.z); o.w = f2bf(v.w);
        if (i < n4A) outA[i] = o; else outB[i - n4A] = o;
    }
}

#define GLD16(g, l) __builtin_amdgcn_global_load_lds( \
    (const __attribute__((address_space(1))) void*)(g), \
    (__attribute__((address_space(3))) void*)(l), 16, 0, 0)

#define MFMA16x16(a, b, c) __builtin_amdgcn_mfma_f32_16x16x32_bf16((a), (b), (c), 0, 0, 0)
#define VMCNT8 asm volatile("s_waitcnt vmcnt(8)" ::: "memory")
#define LGK0   asm volatile("s_waitcnt lgkmcnt(0)" ::: "memory")
#define BAR    __builtin_amdgcn_s_barrier()
#define SCHED0 __builtin_amdgcn_sched_barrier(0)
#define KCLAMP(k) ((k) < NT ? (k) : NT - 1)

// 256x(128low+128high) block tile, BK=64, 512 thr (8 waves: 2M x 4N),
// double-buffered 128 KiB LDS. Gray-coded quadrant phases per K-tile:
//   ph0: Q(A0,B0)  ph1: Q(A0,B1)  ph2: Q(A1,B1)  ph3: Q(A1,B0)
// Each phase: [stage 1 unit; vmcnt(8); barrier; lgkmcnt(0); 16 MFMA;
// ds_reads for the NEXT phase] -- reads drain under the next barrier and
// other waves' MFMA. Single A reg-set (A0/A1 time-share), dual B sets.
// Stage lag = 4-5 phases, uniform vmcnt(8) (2 loads/unit, 4-5 units in flight).
// XOR-swizzled LDS rows (swizzle pre-applied on global src; linear LDS dst).
__global__ __launch_bounds__(512, 1)
void gemm_rope(const unsigned short* __restrict__ Xb,
               const unsigned short* __restrict__ Wb,
               const float* __restrict__ bias,
               float* __restrict__ out)
{
    __shared__ __align__(16) unsigned short As[2][256][64];  // 64 KiB
    __shared__ __align__(16) unsigned short Bs[2][256][64];  // 64 KiB

    const int tid  = threadIdx.x;
    const int lane = tid & 63;
    const int wave = tid >> 6;
    const int wr = wave >> 2;   // 0..1  (row half)
    const int wc = wave & 3;    // 0..3  (col quarter)
    const int fr = lane & 15;
    const int hi = lane >> 4;   // 0..3

    // XCD-aware swizzle (grid=512, 512%8==0 -> bijective)
    const int bid = blockIdx.x;
    const int swz = (bid & 7) * 64 + (bid >> 3);
    const int nb = swz & 7;     // 8 col-pair blocks of 128
    const int mb = swz >> 3;    // 64 row blocks of 256
    const int m0 = mb * 256;
    const int c0 = nb * 128;

    // ---- staging address precompute (linear LDS dst, swizzled global src) ----
    const unsigned short* aSrc[2][2];
    const unsigned short* bSrc[2][2];
    int aDst[2][2], bDst[2][2];
    #pragma unroll
    for (int l = 0; l < 2; ++l) {
        const int c = wave * 128 + l * 64 + lane;       // 16B-chunk index, 0..1023
        // A-unit(qi): rows {qi*64+[0,64)} U {128+qi*64+[0,64)}
        const int seg = c >> 9, within = c & 511;
        const int ris = within >> 3, cch = within & 7;
        const int kch = cch ^ (ris & 7);
        #pragma unroll
        for (int qi = 0; qi < 2; ++qi) {
            const int ldsrow = seg * 128 + qi * 64 + ris;
            aDst[qi][l] = ldsrow * 128 + cch * 16;
            const int grow = m0 + seg * 128 + qi * 64 + ris;
            aSrc[qi][l] = Xb + (size_t)grow * K_DIM + kch * 8;
        }
        // B-unit(qj): rows qj*128+[0,128)
        const int rin = c >> 3, cchb = c & 7;
        const int kchb = cchb ^ (rin & 7);
        #pragma unroll
        for (int qj = 0; qj < 2; ++qj) {
            bDst[qj][l] = (qj * 128 + rin) * 128 + cchb * 16;
            const int wrow = qj * N_HALF + c0 + rin;
            bSrc[qj][l] = Wb + (size_t)wrow * K_DIM + kchb * 8;
        }
    }

#define STAGE_A(q, bb, kk) do { \
    GLD16(aSrc[q][0] + (size_t)(kk) * 64, (char*)&As[bb][0][0] + aDst[q][0]); \
    GLD16(aSrc[q][1] + (size_t)(kk) * 64, (char*)&As[bb][0][0] + aDst[q][1]); \
} while (0)
#define STAGE_B(q, bb, kk) do { \
    GLD16(bSrc[q][0] + (size_t)(kk) * 64, (char*)&Bs[bb][0][0] + bDst[q][0]); \
    GLD16(bSrc[q][1] + (size_t)(kk) * 64, (char*)&Bs[bb][0][0] + bDst[q][1]); \
} while (0)

    // frag-read swizzled k byte-offsets within a 128-B LDS row
    const int xorv = (fr & 7) << 4;
    const int koff0 = (hi * 16) ^ xorv;         // k-slice 0 (k=0..31)
    const int koff1 = (64 + hi * 16) ^ xorv;    // k-slice 1 (k=32..63)

#define RD8(base, row, ko) (*(const bf16x8*)((const char*)(base) + (row) * 128 + (ko)))
#define READ_A(dst, base, rb) do { _Pragma("unroll") \
    for (int i = 0; i < 4; ++i) { \
        dst[i][0] = RD8(base, (rb) + i * 16 + fr, koff0); \
        dst[i][1] = RD8(base, (rb) + i * 16 + fr, koff1); } } while (0)
#define READ_B(dst, base, rb) do { _Pragma("unroll") \
    for (int j = 0; j < 2; ++j) { \
        dst[j][0] = RD8(base, (rb) + j * 16 + fr, koff0); \
        dst[j][1] = RD8(base, (rb) + j * 16 + fr, koff1); } } while (0)

    f32x4 acc[8][4];
    #pragma unroll
    for (int i = 0; i < 8; ++i)
        #pragma unroll
        for (int j = 0; j < 4; ++j)
            acc[i][j] = (f32x4){0.f, 0.f, 0.f, 0.f};

    // aC: time-shared A set (holds A0 in ph0-1, A1 in ph2-3); bX=B0, bY=B1
    bf16x8 aC[4][2], bX[2][2], bY[2][2];

#define CLUSTER(r0, aset, bset, j0) do { \
    __builtin_amdgcn_s_setprio(1); \
    _Pragma("unroll") for (int i = 0; i < 4; ++i) \
      _Pragma("unroll") for (int j = 0; j < 2; ++j) { \
        acc[(r0) + i][(j0) + j] = MFMA16x16(aset[i][0], bset[j][0], acc[(r0) + i][(j0) + j]); \
        acc[(r0) + i][(j0) + j] = MFMA16x16(aset[i][1], bset[j][1], acc[(r0) + i][(j0) + j]); } \
    __builtin_amdgcn_s_setprio(0); } while (0)

    // ph0(t): stage B1(t+1)->nxt; MFMA Q00; read bY<-B1(t)
    // ph1(t): stage A1(t+1)->nxt; MFMA Q01; read aC<-A1(t)
    // ph2(t): stage B0(t+2)->cur; MFMA Q11;           (no reads, no vmcnt)
    // ph3(t): stage A0(t+2)->cur; MFMA Q10; read aC<-A0(t+1), bX<-B0(t+1)
#define PHASE0(cur, nxt, t) do { \
    STAGE_B(1, nxt, KCLAMP((t) + 1)); \
    VMCNT8; BAR; LGK0; SCHED0; \
    CLUSTER(0, aC, bX, 0); \
    READ_B(bY, &Bs[cur][0][0], 128 + wc * 32); } while (0)
#define PHASE1(cur, nxt, t) do { \
    STAGE_A(1, nxt, KCLAMP((t) + 1)); \
    VMCNT8; BAR; LGK0; SCHED0; \
    CLUSTER(0, aC, bY, 2); \
    READ_A(aC, &As[cur][0][0], wr * 128 + 64); } while (0)
#define PHASE2(cur, nxt, t) do { \
    STAGE_B(0, cur, KCLAMP((t) + 2)); \
    BAR; LGK0; SCHED0; \
    CLUSTER(4, aC, bY, 2); } while (0)
#define PHASE3(cur, nxt, t) do { \
    STAGE_A(0, cur, KCLAMP((t) + 2)); \
    VMCNT8; BAR; LGK0; SCHED0; \
    CLUSTER(4, aC, bX, 0); \
    READ_A(aC, &As[nxt][0][0], wr * 128); \
    READ_B(bX, &Bs[nxt][0][0], wc * 32); } while (0)

    // ---- prologue ("virtual tile -1"): prime the stage stream ----
    STAGE_A(0, 0, 0);   // A0(0)
    STAGE_B(0, 0, 0);   // B0(0)
    STAGE_B(1, 0, 0);   // B1(0)
    STAGE_A(1, 0, 0);   // A1(0)
    STAGE_B(0, 1, 1);   // B0(1)
    STAGE_A(0, 1, 1);   // A0(1)
    VMCNT8;             // retires A0(0),B0(0); 8 loads in flight
    BAR;
    READ_A(aC, &As[0][0][0], wr * 128);   // A0(0)
    READ_B(bX, &Bs[0][0][0], wc * 32);    // B0(0)

    for (int ti = 0; ti < NT / 2; ++ti) {
        const int te = 2 * ti, to = te + 1;
        PHASE0(0, 1, te); PHASE1(0, 1, te); PHASE2(0, 1, te); PHASE3(0, 1, te);
        PHASE0(1, 0, to); PHASE1(1, 0, to); PHASE2(1, 0, to); PHASE3(1, 0, to);
    }
    asm volatile("s_waitcnt vmcnt(0)" ::: "memory");  // drain LDS-DMA before epilogue

    // ---- epilogue: bias + RoPE + 2x, fp32 store ----
    // acc[i][cp] (cp=0,1): col ol = c0 + wc*32 + cp*16 + fr; acc[i][cp+2]: col ol+1024.
    // rows: m = m0 + wr*128 + i*16 + hi*4 + r  (block stays within one 4096-seq)
    const float fs0f = (float)((m0 + wr * 128 + hi * 4) & 4095);
    #pragma unroll
    for (int cp = 0; cp < 2; ++cp) {
        const int ol = c0 + wc * 32 + cp * 16 + fr;
        const float invf = exp2f(-L2T * (float)ol);
        const float bl = bias[ol], bh = bias[ol + N_HALF];
        float cs, sn, c1, s1, c13, s13;
        sincosf(fs0f * invf, &sn, &cs);      // base angle
        sincosf(invf, &s1, &c1);             // +1 row step
        sincosf(13.0f * invf, &s13, &c13);   // +13 (frag-boundary) step
        #pragma unroll
        for (int i = 0; i < 8; ++i) {
            #pragma unroll
            for (int r = 0; r < 4; ++r) {
                const int m = m0 + wr * 128 + i * 16 + hi * 4 + r;
                float* orow = out + (size_t)m * K_DIM + ol;
                const float ql = acc[i][cp][r] + bl;
                const float qh = acc[i][cp + 2][r] + bh;
                orow[0]      = 2.0f * (ql * cs - qh * sn);
                orow[N_HALF] = 2.0f * (qh * cs + ql * sn);
                float nc, ns;
                if (r < 3) { nc = cs * c1 - sn * s1;  ns = sn * c1 + cs * s1; }
                else       { nc = cs * c13 - sn * s13; ns = sn * c13 + cs * s13; }
                cs = nc; sn = ns;
            }
        }
    }
}

// Emergency fallback if workspace is too small: slow but correct fp32 path.
__global__ __launch_bounds__(256) void fallback_fused(const float* __restrict__ x,
                                                      const float* __restrict__ W,
                                                      const float* __restrict__ bias,
                                                      float* __restrict__ out)
{
    __shared__ float xs[K_DIM];
    const int m = blockIdx.x;
    const int tid = threadIdx.x;
    for (int k = tid; k < K_DIM; k += 256) xs[k] = x[(size_t)m * K_DIM + k];
    __syncthreads();
    const float fs = (float)(m & 4095);
    for (int ol = tid; ol < N_HALF; ol += 256) {
        const float* wl = W + (size_t)ol * K_DIM;
        const float* wh = W + (size_t)(ol + N_HALF) * K_DIM;
        float al = 0.f, ah = 0.f;
        for (int k = 0; k < K_DIM; ++k) { al += xs[k] * wl[k]; ah += xs[k] * wh[k]; }
        al += bias[ol]; ah += bias[ol + N_HALF];
        float sn, cs;
        sincosf(fs * exp2f(-L2T * (float)ol), &sn, &cs);
        out[(size_t)m * K_DIM + ol]          = 2.0f * (al * cs - ah * sn);
        out[(size_t)m * K_DIM + ol + N_HALF] = 2.0f * (ah * cs + al * sn);
    }
}

extern "C" void kernel_launch(void* const* d_in, const int* in_sizes, int n_in,
                              void* d_out, int out_size, void* d_ws, size_t ws_size,
                              hipStream_t stream)
{
    const float* x = (const float*)d_in[0];
    const float* W = (const float*)d_in[1];
    const float* b = (const float*)d_in[2];
    float* out = (float*)d_out;

    const size_t nx = (size_t)M_TOT * K_DIM;
    const size_t nw = (size_t)K_DIM * K_DIM;
    const size_t need = (nx + nw) * sizeof(unsigned short);
    if (ws_size < need) {
        fallback_fused<<<M_TOT, 256, 0, stream>>>(x, W, b, out);
        return;
    }
    unsigned short* xb = (unsigned short*)d_ws;
    unsigned short* wb = xb + nx;
    cvt_f32_bf16_2<<<2048, 256, 0, stream>>>((const float4*)x, (u16x4*)xb, (int)(nx / 4),
                                             (const float4*)W, (u16x4*)wb, (int)(nw / 4));
    gemm_rope<<<(M_TOT / 256) * (N_HALF / 128), 512, 0, stream>>>(xb, wb, b, out);
}

// Round 7
// 188.233 us; speedup vs baseline: 1.4154x; 1.0030x over previous
//
#include <hip/hip_runtime.h>
#include <cstdint>
#include <cstddef>

#define M_TOT 16384   // B*S = 4*4096
#define K_DIM 2048    // H
#define N_HALF 1024   // H/2
#define NT 32         // K tiles of BK=64
#define L2T 0.012976281620653759f  // log2(10000)/1024

typedef short bf16x8 __attribute__((ext_vector_type(8)));
typedef float f32x4 __attribute__((ext_vector_type(4)));
typedef unsigned short u16x4 __attribute__((ext_vector_type(4)));

__device__ __forceinline__ unsigned short f2bf(float f) {
    unsigned int u = __builtin_bit_cast(unsigned int, f);
    u += 0x7fffu + ((u >> 16) & 1u);   // RNE (no NaN inputs)
    return (unsigned short)(u >> 16);
}

// One launch converts both x and W (fp32 -> bf16), grid-stride.
__global__ __launch_bounds__(256) void cvt_f32_bf16_2(const float4* __restrict__ inA,
                                                      u16x4* __restrict__ outA, int n4A,
                                                      const float4* __restrict__ inB,
                                                      u16x4* __restrict__ outB, int n4B) {
    int idx = blockIdx.x * 256 + threadIdx.x;
    int stride = gridDim.x * 256;
    int tot = n4A + n4B;
    for (int i = idx; i < tot; i += stride) {
        const float4 v = (i < n4A) ? inA[i] : inB[i - n4A];
        u16x4 o;
        o.x = f2bf(v.x); o.y = f2bf(v.y); o.z = f2bf(v.z); o.w = f2bf(v.w);
        if (i < n4A) outA[i] = o; else outB[i - n4A] = o;
    }
}

#define GLD16(g, l) __builtin_amdgcn_global_load_lds( \
    (const __attribute__((address_space(1))) void*)(g), \
    (__attribute__((address_space(3))) void*)(l), 16, 0, 0)

#define MFMA16x16(a, b, c) __builtin_amdgcn_mfma_f32_16x16x32_bf16((a), (b), (c), 0, 0, 0)
#define VMCNT4 asm volatile("s_waitcnt vmcnt(4)" ::: "memory")
#define VMCNT6 asm volatile("s_waitcnt vmcnt(6)" ::: "memory")
#define LGK0   asm volatile("s_waitcnt lgkmcnt(0)" ::: "memory")
#define LGK8   asm volatile("s_waitcnt lgkmcnt(8)" ::: "memory")
#define BAR    __builtin_amdgcn_s_barrier()
#define KCLAMP(k) ((k) < NT ? (k) : NT - 1)

// m201-faithful 8-phase schedule on 256x(128low+128high) tile, BK=64,
// 512 thr (8 waves: 2M x 4N), double-buffered 128 KiB LDS.
// Per phase: [ds_reads for THIS phase's MFMA; stage 1 unit; (lgkmcnt(8) if
// 12 reads); s_barrier; lgkmcnt(0); setprio1; 16 MFMA; setprio0; s_barrier].
// Quadrant Gray order Q(A0,B0)->Q(A0,B1)->Q(A1,B1)->Q(A1,B0); reads/phase
// 12,4,8,0. Stage stream lag 4-7 phases (t+1.A1, t+2.A0, t+2.B0, t+2.B1;
// t+2 units go into the CURRENT buffer's just-consumed regions, legalized by
// the double barrier). ONE vmcnt(6) per K-tile at phase 4, retiring exactly
// tile t+1's four units. XOR-swizzled LDS rows (swizzle on global src).
__global__ __launch_bounds__(512, 1)
void gemm_rope(const unsigned short* __restrict__ Xb,
               const unsigned short* __restrict__ Wb,
               const float* __restrict__ bias,
               float* __restrict__ out)
{
    __shared__ __align__(16) unsigned short As[2][256][64];  // 64 KiB
    __shared__ __align__(16) unsigned short Bs[2][256][64];  // 64 KiB

    const int tid  = threadIdx.x;
    const int lane = tid & 63;
    const int wave = tid >> 6;
    const int wr = wave >> 2;   // 0..1  (row half)
    const int wc = wave & 3;    // 0..3  (col quarter)
    const int fr = lane & 15;
    const int hi = lane >> 4;   // 0..3

    // XCD-aware swizzle (grid=512, 512%8==0 -> bijective)
    const int bid = blockIdx.x;
    const int swz = (bid & 7) * 64 + (bid >> 3);
    const int nb = swz & 7;     // 8 col-pair blocks of 128
    const int mb = swz >> 3;    // 64 row blocks of 256
    const int m0 = mb * 256;
    const int c0 = nb * 128;

    // ---- staging address precompute (linear LDS dst, swizzled global src) ----
    const unsigned short* aSrc[2][2];
    const unsigned short* bSrc[2][2];
    int aDst[2][2], bDst[2][2];
    #pragma unroll
    for (int l = 0; l < 2; ++l) {
        const int c = wave * 128 + l * 64 + lane;       // 16B-chunk index, 0..1023
        // A-unit(qi): rows {qi*64+[0,64)} U {128+qi*64+[0,64)}
        const int seg = c >> 9, within = c & 511;
        const int ris = within >> 3, cch = within & 7;
        const int kch = cch ^ (ris & 7);
        #pragma unroll
        for (int qi = 0; qi < 2; ++qi) {
            const int ldsrow = seg * 128 + qi * 64 + ris;
            aDst[qi][l] = ldsrow * 128 + cch * 16;
            const int grow = m0 + seg * 128 + qi * 64 + ris;
            aSrc[qi][l] = Xb + (size_t)grow * K_DIM + kch * 8;
        }
        // B-unit(qj): rows qj*128+[0,128)
        const int rin = c >> 3, cchb = c & 7;
        const int kchb = cchb ^ (rin & 7);
        #pragma unroll
        for (int qj = 0; qj < 2; ++qj) {
            bDst[qj][l] = (qj * 128 + rin) * 128 + cchb * 16;
            const int wrow = qj * N_HALF + c0 + rin;
            bSrc[qj][l] = Wb + (size_t)wrow * K_DIM + kchb * 8;
        }
    }

#define STAGE_A(q, bb, kk) do { \
    GLD16(aSrc[q][0] + (size_t)(kk) * 64, (char*)&As[bb][0][0] + aDst[q][0]); \
    GLD16(aSrc[q][1] + (size_t)(kk) * 64, (char*)&As[bb][0][0] + aDst[q][1]); \
} while (0)
#define STAGE_B(q, bb, kk) do { \
    GLD16(bSrc[q][0] + (size_t)(kk) * 64, (char*)&Bs[bb][0][0] + bDst[q][0]); \
    GLD16(bSrc[q][1] + (size_t)(kk) * 64, (char*)&Bs[bb][0][0] + bDst[q][1]); \
} while (0)

    // frag-read swizzled k byte-offsets within a 128-B LDS row
    const int xorv = (fr & 7) << 4;
    const int koff0 = (hi * 16) ^ xorv;         // k-slice 0 (k=0..31)
    const int koff1 = (64 + hi * 16) ^ xorv;    // k-slice 1 (k=32..63)

#define RD8(base, row, ko) (*(const bf16x8*)((const char*)(base) + (row) * 128 + (ko)))
#define READ_A(dst, base, rb) do { _Pragma("unroll") \
    for (int i = 0; i < 4; ++i) { \
        dst[i][0] = RD8(base, (rb) + i * 16 + fr, koff0); \
        dst[i][1] = RD8(base, (rb) + i * 16 + fr, koff1); } } while (0)
#define READ_B(dst, base, rb) do { _Pragma("unroll") \
    for (int j = 0; j < 2; ++j) { \
        dst[j][0] = RD8(base, (rb) + j * 16 + fr, koff0); \
        dst[j][1] = RD8(base, (rb) + j * 16 + fr, koff1); } } while (0)

    f32x4 acc[8][4];
    #pragma unroll
    for (int i = 0; i < 8; ++i)
        #pragma unroll
        for (int j = 0; j < 4; ++j)
            acc[i][j] = (f32x4){0.f, 0.f, 0.f, 0.f};

    // aC: time-shared A set (A0 in ph1-2, A1 in ph3-4); bX=B0, bY=B1
    bf16x8 aC[4][2], bX[2][2], bY[2][2];

#define CLUSTER(r0, aset, bset, j0) do { \
    __builtin_amdgcn_s_setprio(1); \
    _Pragma("unroll") for (int i = 0; i < 4; ++i) \
      _Pragma("unroll") for (int j = 0; j < 2; ++j) { \
        acc[(r0) + i][(j0) + j] = MFMA16x16(aset[i][0], bset[j][0], acc[(r0) + i][(j0) + j]); \
        acc[(r0) + i][(j0) + j] = MFMA16x16(aset[i][1], bset[j][1], acc[(r0) + i][(j0) + j]); } \
    __builtin_amdgcn_s_setprio(0); } while (0)

    // ph1(t): read A0,B0 (12); stage A1(t+1)->nxt; lgkm(8); BAR; lgkm0; Q(A0,B0); BAR
    // ph2(t): read B1 (4);     stage A0(t+2)->cur;          BAR; lgkm0; Q(A0,B1); BAR
    // ph3(t): read A1 (8);     stage B0(t+2)->cur;          BAR; lgkm0; Q(A1,B1); BAR
    // ph4(t):                  stage B1(t+2)->cur; vmcnt(6);BAR; lgkm0; Q(A1,B0); BAR
#define PH1(cur, nxt, t) do { \
    READ_A(aC, &As[cur][0][0], wr * 128); \
    READ_B(bX, &Bs[cur][0][0], wc * 32); \
    STAGE_A(1, nxt, KCLAMP((t) + 1)); \
    LGK8; BAR; LGK0; \
    CLUSTER(0, aC, bX, 0); \
    BAR; } while (0)
#define PH2(cur, nxt, t) do { \
    READ_B(bY, &Bs[cur][0][0], 128 + wc * 32); \
    STAGE_A(0, cur, KCLAMP((t) + 2)); \
    BAR; LGK0; \
    CLUSTER(0, aC, bY, 2); \
    BAR; } while (0)
#define PH3(cur, nxt, t) do { \
    READ_A(aC, &As[cur][0][0], wr * 128 + 64); \
    STAGE_B(0, cur, KCLAMP((t) + 2)); \
    BAR; LGK0; \
    CLUSTER(4, aC, bY, 2); \
    BAR; } while (0)
#define PH4(cur, nxt, t) do { \
    STAGE_B(1, cur, KCLAMP((t) + 2)); \
    VMCNT6; BAR; LGK0; \
    CLUSTER(4, aC, bX, 0); \
    BAR; } while (0)

    // ---- prologue (m201: vmcnt(4) after 4 units, vmcnt(6) after +3) ----
    STAGE_A(0, 0, 0);   // t0.A0
    STAGE_B(0, 0, 0);   // t0.B0
    STAGE_B(1, 0, 0);   // t0.B1
    STAGE_A(1, 0, 0);   // t0.A1
    VMCNT4;             // retires t0.A0, t0.B0
    STAGE_A(0, 1, 1);   // t1.A0
    STAGE_B(0, 1, 1);   // t1.B0
    STAGE_B(1, 1, 1);   // t1.B1
    VMCNT6;             // retires t0.B1, t0.A1; leaves t1 trio in flight
    BAR;

    for (int ti = 0; ti < NT / 2; ++ti) {
        const int te = 2 * ti, to = te + 1;
        PH1(0, 1, te); PH2(0, 1, te); PH3(0, 1, te); PH4(0, 1, te);
        PH1(1, 0, to); PH2(1, 0, to); PH3(1, 0, to); PH4(1, 0, to);
    }
    asm volatile("s_waitcnt vmcnt(0)" ::: "memory");  // drain LDS-DMA before epilogue

    // ---- epilogue: bias + RoPE + 2x, fp32 store ----
    // acc[i][cp] (cp=0,1): col ol = c0 + wc*32 + cp*16 + fr; acc[i][cp+2]: col ol+1024.
    // rows: m = m0 + wr*128 + i*16 + hi*4 + r  (block stays within one 4096-seq)
    const float fs0f = (float)((m0 + wr * 128 + hi * 4) & 4095);
    #pragma unroll
    for (int cp = 0; cp < 2; ++cp) {
        const int ol = c0 + wc * 32 + cp * 16 + fr;
        const float invf = exp2f(-L2T * (float)ol);
        const float bl = bias[ol], bh = bias[ol + N_HALF];
        float cs, sn, c1, s1, c13, s13;
        sincosf(fs0f * invf, &sn, &cs);      // base angle
        sincosf(invf, &s1, &c1);             // +1 row step
        sincosf(13.0f * invf, &s13, &c13);   // +13 (frag-boundary) step
        #pragma unroll
        for (int i = 0; i < 8; ++i) {
            #pragma unroll
            for (int r = 0; r < 4; ++r) {
                const int m = m0 + wr * 128 + i * 16 + hi * 4 + r;
                float* orow = out + (size_t)m * K_DIM + ol;
                const float ql = acc[i][cp][r] + bl;
                const float qh = acc[i][cp + 2][r] + bh;
                orow[0]      = 2.0f * (ql * cs - qh * sn);
                orow[N_HALF] = 2.0f * (qh * cs + ql * sn);
                float nc, ns;
                if (r < 3) { nc = cs * c1 - sn * s1;  ns = sn * c1 + cs * s1; }
                else       { nc = cs * c13 - sn * s13; ns = sn * c13 + cs * s13; }
                cs = nc; sn = ns;
            }
        }
    }
}

// Emergency fallback if workspace is too small: slow but correct fp32 path.
__global__ __launch_bounds__(256) void fallback_fused(const float* __restrict__ x,
                                                      const float* __restrict__ W,
                                                      const float* __restrict__ bias,
                                                      float* __restrict__ out)
{
    __shared__ float xs[K_DIM];
    const int m = blockIdx.x;
    const int tid = threadIdx.x;
    for (int k = tid; k < K_DIM; k += 256) xs[k] = x[(size_t)m * K_DIM + k];
    __syncthreads();
    const float fs = (float)(m & 4095);
    for (int ol = tid; ol < N_HALF; ol += 256) {
        const float* wl = W + (size_t)ol * K_DIM;
        const float* wh = W + (size_t)(ol + N_HALF) * K_DIM;
        float al = 0.f, ah = 0.f;
        for (int k = 0; k < K_DIM; ++k) { al += xs[k] * wl[k]; ah += xs[k] * wh[k]; }
        al += bias[ol]; ah += bias[ol + N_HALF];
        float sn, cs;
        sincosf(fs * exp2f(-L2T * (float)ol), &sn, &cs);
        out[(size_t)m * K_DIM + ol]          = 2.0f * (al * cs - ah * sn);
        out[(size_t)m * K_DIM + ol + N_HALF] = 2.0f * (ah * cs + al * sn);
    }
}

extern "C" void kernel_launch(void* const* d_in, const int* in_sizes, int n_in,
                              void* d_out, int out_size, void* d_ws, size_t ws_size,
                              hipStream_t stream)
{
    const float* x = (const float*)d_in[0];
    const float* W = (const float*)d_in[1];
    const float* b = (const float*)d_in[2];
    float* out = (float*)d_out;

    const size_t nx = (size_t)M_TOT * K_DIM;
    const size_t nw = (size_t)K_DIM * K_DIM;
    const size_t need = (nx + nw) * sizeof(unsigned short);
    if (ws_size < need) {
        fallback_fused<<<M_TOT, 256, 0, stream>>>(x, W, b, out);
        return;
    }
    unsigned short* xb = (unsigned short*)d_ws;
    unsigned short* wb = xb + nx;
    cvt_f32_bf16_2<<<2048, 256, 0, stream>>>((const float4*)x, (u16x4*)xb, (int)(nx / 4),
                                             (const float4*)W, (u16x4*)wb, (int)(nw / 4));
    gemm_rope<<<(M_TOT / 256) * (N_HALF / 128), 512, 0, stream>>>(xb, wb, b, out);
}

// Round 8
// 169.967 us; speedup vs baseline: 1.5675x; 1.1075x over previous
//
#include <hip/hip_runtime.h>
#include <cstdint>
#include <cstddef>

#define M_TOT 16384   // B*S = 4*4096
#define K_DIM 2048    // H
#define N_HALF 1024   // H/2
#define NT 32         // K tiles of BK=64
#define L2T 0.012976281620653759f  // log2(10000)/1024

typedef short bf16x8 __attribute__((ext_vector_type(8)));
typedef float f32x4 __attribute__((ext_vector_type(4)));
typedef unsigned short u16x4 __attribute__((ext_vector_type(4)));

__device__ __forceinline__ unsigned short f2bf(float f) {
    unsigned int u = __builtin_bit_cast(unsigned int, f);
    u += 0x7fffu + ((u >> 16) & 1u);   // RNE (no NaN inputs)
    return (unsigned short)(u >> 16);
}

// One launch converts both x and W (fp32 -> bf16), grid-stride.
__global__ __launch_bounds__(256) void cvt_f32_bf16_2(const float4* __restrict__ inA,
                                                      u16x4* __restrict__ outA, int n4A,
                                                      const float4* __restrict__ inB,
                                                      u16x4* __restrict__ outB, int n4B) {
    int idx = blockIdx.x * 256 + threadIdx.x;
    int stride = gridDim.x * 256;
    int tot = n4A + n4B;
    for (int i = idx; i < tot; i += stride) {
        const float4 v = (i < n4A) ? inA[i] : inB[i - n4A];
        u16x4 o;
        o.x = f2bf(v.x); o.y = f2bf(v.y); o.z = f2bf(v.z); o.w = f2bf(v.w);
        if (i < n4A) outA[i] = o; else outB[i - n4A] = o;
    }
}

#define GLD16(g, l) __builtin_amdgcn_global_load_lds( \
    (const __attribute__((address_space(1))) void*)(g), \
    (__attribute__((address_space(3))) void*)(l), 16, 0, 0)

#define MFMA16x16(a, b, c) __builtin_amdgcn_mfma_f32_16x16x32_bf16((a), (b), (c), 0, 0, 0)
#define VMCNT4 asm volatile("s_waitcnt vmcnt(4)" ::: "memory")
#define LGK0   asm volatile("s_waitcnt lgkmcnt(0)" ::: "memory")
#define LGK8   asm volatile("s_waitcnt lgkmcnt(8)" ::: "memory")
#define BAR    __builtin_amdgcn_s_barrier()
#define SCHED0 __builtin_amdgcn_sched_barrier(0)

// R4 structure (best known: 143.6us, no spill) with ONE change: lgkmcnt(0)
// moved AFTER the barrier (waves signal after ISSUING reads; own-read drain
// overlaps the barrier wait instead of serializing before it). 12-read phase
// gets a partial lgkmcnt(8) before the barrier, per the m201 template.
// Safety: every wave's reads of buf are drained at its post-BAR lgkmcnt(0),
// which precedes its next barrier signal; all stages target nbuf only.
__global__ __launch_bounds__(512, 2)
void gemm_rope(const unsigned short* __restrict__ Xb,
               const unsigned short* __restrict__ Wb,
               const float* __restrict__ bias,
               float* __restrict__ out)
{
    __shared__ __align__(16) unsigned short As[2][256][64];  // 64 KiB
    __shared__ __align__(16) unsigned short Bs[2][256][64];  // 64 KiB

    const int tid  = threadIdx.x;
    const int lane = tid & 63;
    const int wave = tid >> 6;
    const int wr = wave >> 2;   // 0..1  (row half)
    const int wc = wave & 3;    // 0..3  (col quarter)
    const int fr = lane & 15;
    const int hi = lane >> 4;   // 0..3

    // XCD-aware swizzle (grid=512, 512%8==0 -> bijective)
    const int bid = blockIdx.x;
    const int swz = (bid & 7) * 64 + (bid >> 3);
    const int nb = swz & 7;     // 8 col-pair blocks of 128
    const int mb = swz >> 3;    // 64 row blocks of 256
    const int m0 = mb * 256;
    const int c0 = nb * 128;

    // ---- staging address precompute (linear LDS dst, swizzled global src) ----
    const unsigned short* aSrc[2][2];
    const unsigned short* bSrc[2][2];
    int aDst[2][2], bDst[2][2];
    #pragma unroll
    for (int l = 0; l < 2; ++l) {
        const int c = wave * 128 + l * 64 + lane;       // 16B-chunk index, 0..1023
        // A-unit(qi): rows {qi*64+[0,64)} U {128+qi*64+[0,64)}
        const int seg = c >> 9, within = c & 511;
        const int ris = within >> 3, cch = within & 7;
        const int kch = cch ^ (ris & 7);
        #pragma unroll
        for (int qi = 0; qi < 2; ++qi) {
            const int ldsrow = seg * 128 + qi * 64 + ris;
            aDst[qi][l] = ldsrow * 128 + cch * 16;
            const int grow = m0 + seg * 128 + qi * 64 + ris;
            aSrc[qi][l] = Xb + (size_t)grow * K_DIM + kch * 8;
        }
        // B-unit(qj): rows qj*128+[0,128)
        const int rin = c >> 3, cchb = c & 7;
        const int kchb = cchb ^ (rin & 7);
        #pragma unroll
        for (int qj = 0; qj < 2; ++qj) {
            bDst[qj][l] = (qj * 128 + rin) * 128 + cchb * 16;
            const int wrow = qj * N_HALF + c0 + rin;
            bSrc[qj][l] = Wb + (size_t)wrow * K_DIM + kchb * 8;
        }
    }

#define STAGE_A(q, bb, kk) do { \
    GLD16(aSrc[q][0] + (size_t)(kk) * 64, (char*)&As[bb][0][0] + aDst[q][0]); \
    GLD16(aSrc[q][1] + (size_t)(kk) * 64, (char*)&As[bb][0][0] + aDst[q][1]); \
} while (0)
#define STAGE_B(q, bb, kk) do { \
    GLD16(bSrc[q][0] + (size_t)(kk) * 64, (char*)&Bs[bb][0][0] + bDst[q][0]); \
    GLD16(bSrc[q][1] + (size_t)(kk) * 64, (char*)&Bs[bb][0][0] + bDst[q][1]); \
} while (0)

    // frag-read swizzled k byte-offsets within a 128-B LDS row
    const int xorv = (fr & 7) << 4;
    const int koff0 = (hi * 16) ^ xorv;         // k-slice 0 (k=0..31)
    const int koff1 = (64 + hi * 16) ^ xorv;    // k-slice 1 (k=32..63)

    f32x4 acc[8][4];
    #pragma unroll
    for (int i = 0; i < 8; ++i)
        #pragma unroll
        for (int j = 0; j < 4; ++j)
            acc[i][j] = (f32x4){0.f, 0.f, 0.f, 0.f};

    bf16x8 aF[4][2], b0F[2][2], b1F[2][2];

    // ---- prologue: tile 0 -> buf 0, unit order A0,B0,B1,A1 ----
    STAGE_A(0, 0, 0); STAGE_B(0, 0, 0); STAGE_B(1, 0, 0); STAGE_A(1, 0, 0);
    VMCNT4;   // A0,B0 of tile 0 landed (B1,A1 may be in flight)
    BAR;

    for (int kt = 0; kt < NT; ++kt) {
        const int buf = kt & 1, nbuf = buf ^ 1;
        const int kp1 = (kt + 1 < NT) ? kt + 1 : NT - 1;  // clamped: harmless dead stage at tail

        // ---- phase 0: read A0+B0 (12); stage A0(kt+1)->nbuf; MFMA acc[0..3][0..1] ----
        {
            const int rb = wr * 128 + fr;
            #pragma unroll
            for (int i = 0; i < 4; ++i) {
                aF[i][0] = *(const bf16x8*)((const char*)&As[buf][0][0] + (rb + i * 16) * 128 + koff0);
                aF[i][1] = *(const bf16x8*)((const char*)&As[buf][0][0] + (rb + i * 16) * 128 + koff1);
            }
            const int cb = wc * 32 + fr;
            #pragma unroll
            for (int j = 0; j < 2; ++j) {
                b0F[j][0] = *(const bf16x8*)((const char*)&Bs[buf][0][0] + (cb + j * 16) * 128 + koff0);
                b0F[j][1] = *(const bf16x8*)((const char*)&Bs[buf][0][0] + (cb + j * 16) * 128 + koff1);
            }
            STAGE_A(0, nbuf, kp1);
            VMCNT4; LGK8; BAR; LGK0; SCHED0;
            __builtin_amdgcn_s_setprio(1);
            #pragma unroll
            for (int i = 0; i < 4; ++i)
                #pragma unroll
                for (int j = 0; j < 2; ++j) {
                    acc[i][j] = MFMA16x16(aF[i][0], b0F[j][0], acc[i][j]);
                    acc[i][j] = MFMA16x16(aF[i][1], b0F[j][1], acc[i][j]);
                }
            __builtin_amdgcn_s_setprio(0);
        }
        // ---- phase 1: read B1 (4); stage B0(kt+1)->nbuf; MFMA acc[0..3][2..3] ----
        {
            const int cb = 128 + wc * 32 + fr;
            #pragma unroll
            for (int j = 0; j < 2; ++j) {
                b1F[j][0] = *(const bf16x8*)((const char*)&Bs[buf][0][0] + (cb + j * 16) * 128 + koff0);
                b1F[j][1] = *(const bf16x8*)((const char*)&Bs[buf][0][0] + (cb + j * 16) * 128 + koff1);
            }
            STAGE_B(0, nbuf, kp1);
            VMCNT4; BAR; LGK0; SCHED0;
            __builtin_amdgcn_s_setprio(1);
            #pragma unroll
            for (int i = 0; i < 4; ++i)
                #pragma unroll
                for (int j = 0; j < 2; ++j) {
                    acc[i][2 + j] = MFMA16x16(aF[i][0], b1F[j][0], acc[i][2 + j]);
                    acc[i][2 + j] = MFMA16x16(aF[i][1], b1F[j][1], acc[i][2 + j]);
                }
            __builtin_amdgcn_s_setprio(0);
        }
        // ---- phase 2: read A1 (8); stage B1(kt+1)->nbuf; MFMA acc[4..7][0..1] ----
        {
            const int rb = wr * 128 + 64 + fr;
            #pragma unroll
            for (int i = 0; i < 4; ++i) {
                aF[i][0] = *(const bf16x8*)((const char*)&As[buf][0][0] + (rb + i * 16) * 128 + koff0);
                aF[i][1] = *(const bf16x8*)((const char*)&As[buf][0][0] + (rb + i * 16) * 128 + koff1);
            }
            STAGE_B(1, nbuf, kp1);
            VMCNT4; BAR; LGK0; SCHED0;
            __builtin_amdgcn_s_setprio(1);
            #pragma unroll
            for (int i = 0; i < 4; ++i)
                #pragma unroll
                for (int j = 0; j < 2; ++j) {
                    acc[4 + i][j] = MFMA16x16(aF[i][0], b0F[j][0], acc[4 + i][j]);
                    acc[4 + i][j] = MFMA16x16(aF[i][1], b0F[j][1], acc[4 + i][j]);
                }
            __builtin_amdgcn_s_setprio(0);
        }
        // ---- phase 3: stage A1(kt+1)->nbuf; MFMA acc[4..7][2..3] ----
        {
            STAGE_A(1, nbuf, kp1);
            VMCNT4; BAR; SCHED0;
            __builtin_amdgcn_s_setprio(1);
            #pragma unroll
            for (int i = 0; i < 4; ++i)
                #pragma unroll
                for (int j = 0; j < 2; ++j) {
                    acc[4 + i][2 + j] = MFMA16x16(aF[i][0], b1F[j][0], acc[4 + i][2 + j]);
                    acc[4 + i][2 + j] = MFMA16x16(aF[i][1], b1F[j][1], acc[4 + i][2 + j]);
                }
            __builtin_amdgcn_s_setprio(0);
        }
    }
    asm volatile("s_waitcnt vmcnt(0)" ::: "memory");  // drain LDS-DMA before epilogue

    // ---- epilogue: bias + RoPE + 2x, fp32 store ----
    // acc[i][cp] (cp=0,1): col ol = c0 + wc*32 + cp*16 + fr; acc[i][cp+2]: col ol+1024.
    // rows: m = m0 + wr*128 + i*16 + hi*4 + r  (block stays within one 4096-seq)
    const float fs0f = (float)((m0 + wr * 128 + hi * 4) & 4095);
    #pragma unroll
    for (int cp = 0; cp < 2; ++cp) {
        const int ol = c0 + wc * 32 + cp * 16 + fr;
        const float invf = exp2f(-L2T * (float)ol);
        const float bl = bias[ol], bh = bias[ol + N_HALF];
        float cs, sn, c1, s1, c13, s13;
        sincosf(fs0f * invf, &sn, &cs);      // base angle
        sincosf(invf, &s1, &c1);             // +1 row step
        sincosf(13.0f * invf, &s13, &c13);   // +13 (frag-boundary) step
        #pragma unroll
        for (int i = 0; i < 8; ++i) {
            #pragma unroll
            for (int r = 0; r < 4; ++r) {
                const int m = m0 + wr * 128 + i * 16 + hi * 4 + r;
                float* orow = out + (size_t)m * K_DIM + ol;
                const float ql = acc[i][cp][r] + bl;
                const float qh = acc[i][cp + 2][r] + bh;
                orow[0]      = 2.0f * (ql * cs - qh * sn);
                orow[N_HALF] = 2.0f * (qh * cs + ql * sn);
                float nc, ns;
                if (r < 3) { nc = cs * c1 - sn * s1;  ns = sn * c1 + cs * s1; }
                else       { nc = cs * c13 - sn * s13; ns = sn * c13 + cs * s13; }
                cs = nc; sn = ns;
            }
        }
    }
}

// Emergency fallback if workspace is too small: slow but correct fp32 path.
__global__ __launch_bounds__(256) void fallback_fused(const float* __restrict__ x,
                                                      const float* __restrict__ W,
                                                      const float* __restrict__ bias,
                                                      float* __restrict__ out)
{
    __shared__ float xs[K_DIM];
    const int m = blockIdx.x;
    const int tid = threadIdx.x;
    for (int k = tid; k < K_DIM; k += 256) xs[k] = x[(size_t)m * K_DIM + k];
    __syncthreads();
    const float fs = (float)(m & 4095);
    for (int ol = tid; ol < N_HALF; ol += 256) {
        const float* wl = W + (size_t)ol * K_DIM;
        const float* wh = W + (size_t)(ol + N_HALF) * K_DIM;
        float al = 0.f, ah = 0.f;
        for (int k = 0; k < K_DIM; ++k) { al += xs[k] * wl[k]; ah += xs[k] * wh[k]; }
        al += bias[ol]; ah += bias[ol + N_HALF];
        float sn, cs;
        sincosf(fs * exp2f(-L2T * (float)ol), &sn, &cs);
        out[(size_t)m * K_DIM + ol]          = 2.0f * (al * cs - ah * sn);
        out[(size_t)m * K_DIM + ol + N_HALF] = 2.0f * (ah * cs + al * sn);
    }
}

extern "C" void kernel_launch(void* const* d_in, const int* in_sizes, int n_in,
                              void* d_out, int out_size, void* d_ws, size_t ws_size,
                              hipStream_t stream)
{
    const float* x = (const float*)d_in[0];
    const float* W = (const float*)d_in[1];
    const float* b = (const float*)d_in[2];
    float* out = (float*)d_out;

    const size_t nx = (size_t)M_TOT * K_DIM;
    const size_t nw = (size_t)K_DIM * K_DIM;
    const size_t need = (nx + nw) * sizeof(unsigned short);
    if (ws_size < need) {
        fallback_fused<<<M_TOT, 256, 0, stream>>>(x, W, b, out);
        return;
    }
    unsigned short* xb = (unsigned short*)d_ws;
    unsigned short* wb = xb + nx;
    cvt_f32_bf16_2<<<2048, 256, 0, stream>>>((const float4*)x, (u16x4*)xb, (int)(nx / 4),
                                             (const float4*)W, (u16x4*)wb, (int)(nw / 4));
    gemm_rope<<<(M_TOT / 256) * (N_HALF / 128), 512, 0, stream>>>(xb, wb, b, out);
}